// Round 12
// baseline (173.589 us; speedup 1.0000x reference)
//
#include <hip/hip_runtime.h>
#include <hip/hip_bf16.h>
#include <math.h>
#include <stdint.h>

// Problem constants
#define NB   2
#define NC   256
#define NSP  4096      // H*W
#define NUSP 1024      // Hu*Wu
#define NHEADS 8
#define HDIM 32
constexpr float SCL  = 0.17677669529663687f;   // 32^-0.5
constexpr float QSCL = 0.17677669529663687f * 1.4426950408889634f;  // SCL*log2(e)

typedef short short8 __attribute__((ext_vector_type(8)));
typedef float f32x4  __attribute__((ext_vector_type(4)));

__device__ __forceinline__ float fexp2(float x) {
#if __has_builtin(__builtin_amdgcn_exp2f)
  return __builtin_amdgcn_exp2f(x);
#else
  return exp2f(x);
#endif
}

// ---------- scratch (device globals referenced ONLY from device code) ----------
__device__ __align__(16) float g_kv    [NB * 512 * NUSP];  // conv-kv f32 [b][o=512][m]
__device__ __align__(16) float g_qm    [NB * NHEADS * HDIM];
__device__ __align__(16) float g_vpe   [NB * NC * NSP];    // [b][c][n]
// bf16 MFMA layouts
__device__ __align__(16) short g_qbf   [NB * NHEADS * NSP * HDIM];  // [bh][n][d] (pre-scaled SCL*log2e)
__device__ __align__(16) short g_kbf   [NB * NHEADS * NUSP * HDIM]; // [bh][m][d]
__device__ __align__(16) short g_vbf   [NB * NHEADS * HDIM * NUSP]; // [bh][d][m]
__device__ __align__(16) short g_tkKbf [NB * NHEADS * 16 * 32];     // [bh][key][d]
__device__ __align__(16) short g_tkVT  [NB * NHEADS * 32 * 32];     // [bh][d][keypad32]
__device__ __align__(16) short g_xT    [NB * NSP * 256];   // x^T   [b][n][c]
__device__ __align__(16) short g_uT    [NB * NUSP * 256];  // upper^T [b][m][c]
__device__ __align__(16) short g_sumT  [NB * NSP * 256];   // (attn+vpe)^T [b][n][c]
__device__ __align__(16) short g_wbf   [262144];           // Wq | Wkv | Wproj
__device__ __align__(16) short g_wgbf  [2048];             // Wg [32][64]

// f32 -> bf16 round-half-up
__device__ __forceinline__ short f2bf(float f) {
  return (short)((__float_as_uint(f) + 0x8000u) >> 16);
}

// pack two f32 -> two bf16 in a u32 (same round-half-up as f2bf)
__device__ __forceinline__ uint32_t pk2bf(float a, float b) {
  uint32_t lo = (__float_as_uint(a) + 0x8000u) >> 16;
  uint32_t hi = (__float_as_uint(b) + 0x8000u) & 0xffff0000u;
  return lo | hi;
}

// ---------- threefry2x32, key = (0, 42) ----------
__device__ __forceinline__ void threefry2x32_042(uint32_t x0, uint32_t x1,
                                                 uint32_t& r0, uint32_t& r1) {
  const uint32_t ks0 = 0u, ks1 = 42u, ks2 = 0u ^ 42u ^ 0x1BD11BDAu;
  x0 += ks0; x1 += ks1;
#define TFR(R) { x0 += x1; x1 = (x1 << (R)) | (x1 >> (32 - (R))); x1 ^= x0; }
  TFR(13) TFR(15) TFR(26) TFR(6)  x0 += ks1; x1 += ks2 + 1u;
  TFR(17) TFR(29) TFR(16) TFR(24) x0 += ks2; x1 += ks0 + 2u;
  TFR(13) TFR(15) TFR(26) TFR(6)  x0 += ks0; x1 += ks1 + 3u;
  TFR(17) TFR(29) TFR(16) TFR(24) x0 += ks1; x1 += ks2 + 4u;
  TFR(13) TFR(15) TFR(26) TFR(6)  x0 += ks2; x1 += ks0 + 5u;
#undef TFR
  r0 = x0; r1 = x1;
}

// gumbel, jax_threefry_partitionable path (verified round 5)
__device__ __forceinline__ float gumbel_at(uint32_t i) {
  uint32_t y0, y1;
  threefry2x32_042(0u, i, y0, y1);
  uint32_t bits = y0 ^ y1;
  uint32_t fb = (bits >> 9) | 0x3f800000u;
  float u = __uint_as_float(fb) - 1.0f;
  u = fmaxf(u, 1.17549435e-38f);
  return -logf(-logf(u));
}

// ---------- k_pack_in v2: fine grid (round-10, confirmed) ----------
__global__ __launch_bounds__(256) void k_pack_in(const float* __restrict__ x,
                                                 const float* __restrict__ upper,
                                                 const float* __restrict__ Wq,
                                                 const float* __restrict__ Wkv,
                                                 const float* __restrict__ Wproj,
                                                 const float* __restrict__ Wg) {
  const int blk = blockIdx.x;
  const int tid = threadIdx.x;
  if (blk < 1280) {
    __shared__ float Ls[32][65];
    const float* src;
    short* dst;
    int b, n0, Nsp, cc;
    if (blk < 1024) { int sec = blk >> 3; cc = blk & 7;
                      b = sec >> 6; n0 = (sec & 63) * 64; Nsp = NSP;
                      src = x + (size_t)b * 256 * NSP;  dst = g_xT + (size_t)b * NSP * 256; }
    else            { int s2 = (blk - 1024) >> 3; cc = (blk - 1024) & 7;
                      b = s2 >> 4; n0 = (s2 & 15) * 64; Nsp = NUSP;
                      src = upper + (size_t)b * 256 * NUSP; dst = g_uT + (size_t)b * NUSP * 256; }
    for (int i = tid; i < 2048; i += 256) {
      int d = i >> 6, nl = i & 63;
      Ls[d][nl] = src[(size_t)(cc * 32 + d) * Nsp + n0 + nl];
    }
    __syncthreads();
    int nl = tid >> 2, dseg = (tid & 3) * 8;
    short8 v;
    #pragma unroll
    for (int j = 0; j < 8; j++) v[j] = f2bf(Ls[dseg + j][nl]);
    *(short8*)&dst[(size_t)(n0 + nl) * 256 + cc * 32 + dseg] = v;
  } else {
    const int sec = blk - 1280;   // 0..31
    if (sec == 0) {
      for (int i = tid; i < 512; i += 256) g_qm[i] = 0.f;
      #pragma unroll
      for (int j = 0; j < 8; j++) g_wgbf[tid * 8 + j] = f2bf(Wg[tid * 8 + j]);
    }
    int base = sec * 8192 + tid * 32;
    const float* s;
    if (base < 65536)       s = Wq + base;
    else if (base < 196608) s = Wkv + (base - 65536);
    else                    s = Wproj + (base - 196608);
    short* d = g_wbf + base;
    #pragma unroll
    for (int j = 0; j < 8; j++) {
      float4 f = *(const float4*)&s[j * 4];
      d[j*4+0] = f2bf(f.x); d[j*4+1] = f2bf(f.y);
      d[j*4+2] = f2bf(f.z); d[j*4+3] = f2bf(f.w);
    }
  }
}

// ---------- B-operand LDS staging (round-9, confirmed -17us) ----------
__device__ __forceinline__ void stage_xt(short Xs[64][264],
                                         const short* __restrict__ ST,
                                         int b, int n0, int Nsp, int tid) {
  const short* src = ST + ((size_t)b * Nsp + n0) * 256;
  #pragma unroll
  for (int i = 0; i < 8; i++) {
    int idx = tid + i * 256;             // 0..2047 = 64 rows x 32 segs
    int row = idx >> 5, seg = (idx & 31) * 8;
    *(short8*)&Xs[row][seg] = *(const short8*)&src[(size_t)row * 256 + seg];
  }
  __syncthreads();
}

// round-12: W-prefetch REVERTED (round-11: +64 VGPR pushed k_gemms over the
// 128-VGPR occupancy cliff, waves/SIMD 4->2; cost > the one-time W-load win).
__device__ __forceinline__ void gemm_mfma_lds(const short* __restrict__ Wbf,
                                              const short Xs[64][264],
                                              int o0, int w, int col, int quad,
                                              f32x4 acc[4]) {
  const short* wrow = Wbf + (size_t)(o0 + w * 16 + col) * 256 + quad * 8;
  #pragma unroll
  for (int kc = 0; kc < 8; kc++) {
    short8 af = *(const short8*)&wrow[kc * 32];
    #pragma unroll
    for (int t = 0; t < 4; t++) {
      short8 bf = *(const short8*)&Xs[t * 16 + col][kc * 32 + quad * 8];
      acc[t] = __builtin_amdgcn_mfma_f32_16x16x32_bf16(af, bf, acc[t], 0, 0, 0);
    }
  }
}

// ---------- k_gemms: q conv (blocks 0..511) + kv conv (512..767), merged ----------
__global__ __launch_bounds__(256) void k_gemms(const float* __restrict__ bq,
                                               const float* __restrict__ bkv) {
  __shared__ float Ls[64][65];
  __shared__ __align__(16) short Xs[64][264];
  const int bx = blockIdx.x;
  const int tid = threadIdx.x;
  const int lane = tid & 63, w = tid >> 6, col = lane & 15, quad = lane >> 4;
  f32x4 acc[4] = {{0,0,0,0},{0,0,0,0},{0,0,0,0},{0,0,0,0}};

  if (bx < 512) {
    const int b = bx >> 8, o0 = ((bx >> 6) & 3) * 64, n0 = (bx & 63) * 64;
    stage_xt(Xs, g_xT, b, n0, NSP, tid);
    gemm_mfma_lds(g_wbf, Xs, o0, w, col, quad, acc);
    float sums[4];
    #pragma unroll
    for (int r = 0; r < 4; r++) {
      int ol = w * 16 + quad * 4 + r;
      float bv = bq[o0 + ol];
      float s = 0.f;
      #pragma unroll
      for (int t = 0; t < 4; t++) {
        float val = acc[t][r] + bv;
        Ls[ol][t * 16 + col] = val;
        s += val;
      }
      sums[r] = s;
    }
    #pragma unroll
    for (int st = 1; st < 16; st <<= 1)
      #pragma unroll
      for (int r = 0; r < 4; r++) sums[r] += __shfl_xor(sums[r], st, 64);
    if (col == 0) {
      #pragma unroll
      for (int r = 0; r < 4; r++)
        atomicAdd(&g_qm[b * 256 + o0 + w * 16 + quad * 4 + r], sums[r] * (1.0f / 4096.0f));
    }
    __syncthreads();
    int nl = tid >> 2, dseg = (tid & 3) * 8;
    #pragma unroll
    for (int hh = 0; hh < 2; hh++) {
      short8 v;
      #pragma unroll
      for (int j = 0; j < 8; j++) v[j] = f2bf(Ls[hh * 32 + dseg + j][nl] * QSCL);
      int bh = b * 8 + ((o0 + hh * 32) >> 5);
      *(short8*)&g_qbf[((size_t)bh * NSP + n0 + nl) * 32 + dseg] = v;
    }
  } else {
    const int idx = bx - 512;
    const int b = idx >> 7, o0 = ((idx >> 4) & 7) * 64, n0 = (idx & 15) * 64;
    stage_xt(Xs, g_uT, b, n0, NUSP, tid);
    gemm_mfma_lds(g_wbf + 65536, Xs, o0, w, col, quad, acc);
    #pragma unroll
    for (int r = 0; r < 4; r++) {
      int ol = w * 16 + quad * 4 + r;
      float bv = bkv[o0 + ol];
      float* orow = g_kv + ((size_t)b * 512 + o0 + ol) * NUSP + n0;
      #pragma unroll
      for (int t = 0; t < 4; t++) {
        float val = acc[t][r] + bv;
        orow[t * 16 + col] = val;
        Ls[ol][t * 16 + col] = val;
      }
    }
    __syncthreads();
    const int bh = b * 8 + (o0 >> 6);
    {  // k rows [0,32) -> kbf transpose
      int m = tid >> 2, dseg = (tid & 3) * 8;
      short8 v;
      #pragma unroll
      for (int j = 0; j < 8; j++) v[j] = f2bf(Ls[dseg + j][m]);
      *(short8*)&g_kbf[((size_t)bh * NUSP + n0 + m) * 32 + dseg] = v;
    }
    {  // v rows [32,64) -> vbf straight
      int d = tid >> 3, m8 = (tid & 7) * 8;
      short8 v;
      #pragma unroll
      for (int j = 0; j < 8; j++) v[j] = f2bf(Ls[32 + d][m8 + j]);
      *(short8*)&g_vbf[((size_t)bh * 32 + d) * NUSP + n0 + m8] = v;
    }
  }
}

// ---------- k_mid: topk (blocks 0..15) + vpe (16..527), merged ----------
union MidSmem {
  struct {
    float zbuf[1024]; float qml[32]; float rv[256]; int ri[256];
    int chosen[4]; int pos[16]; float xg[16][256]; float wl[64][65];
  } t;
  struct {
    float src[32][33]; float pl[32][33]; float wk[49];
  } v;
};

__global__ __launch_bounds__(256) void k_mid(const float* __restrict__ x,
                                             const float* __restrict__ Wkv,
                                             const float* __restrict__ bkv,
                                             const float* __restrict__ Wpe,
                                             const float* __restrict__ bpe) {
  __shared__ MidSmem sm;
  const int tid = threadIdx.x;
  if (blockIdx.x < 16) {
    // ================= topk =================
    const int bh = blockIdx.x;
    const int b = bh >> 3, h = bh & 7;
    if (tid < 32) sm.t.qml[tid] = g_qm[bh * 32 + tid];
    __syncthreads();
    const float* kbase = g_kv + ((size_t)b * 512 + h * 64) * NUSP;
    float zv[4];
    #pragma unroll
    for (int r = 0; r < 4; r++) {
      int m = r * 256 + tid;
      float dot = 0.f;
      #pragma unroll 8
      for (int d = 0; d < 32; d++) dot += sm.t.qml[d] * kbase[(size_t)d * NUSP + m];
      float z = dot * SCL + gumbel_at((uint32_t)(bh * 1024 + m));
      zv[r] = z; sm.t.zbuf[m] = z;
    }
    __syncthreads();
    float mx = fmaxf(fmaxf(zv[0], zv[1]), fmaxf(zv[2], zv[3]));
    sm.t.rv[tid] = mx; __syncthreads();
    for (int st = 128; st > 0; st >>= 1) {
      if (tid < st) sm.t.rv[tid] = fmaxf(sm.t.rv[tid], sm.t.rv[tid + st]);
      __syncthreads();
    }
    float zmax = sm.t.rv[0]; __syncthreads();
    float sp = 0.f; float ev[4];
    #pragma unroll
    for (int r = 0; r < 4; r++) { ev[r] = __expf(zv[r] - zmax); sp += ev[r]; }
    sm.t.rv[tid] = sp; __syncthreads();
    for (int st = 128; st > 0; st >>= 1) {
      if (tid < st) sm.t.rv[tid] += sm.t.rv[tid + st];
      __syncthreads();
    }
    float ssum = sm.t.rv[0]; __syncthreads();
    #pragma unroll
    for (int r = 0; r < 4; r++) sm.t.zbuf[r * 256 + tid] = ev[r] / ssum;
    __syncthreads();
    for (int t = 0; t < 4; t++) {
      float bv = -2.0f; int bi = 0;
      #pragma unroll
      for (int r = 0; r < 4; r++) {
        int m = r * 256 + tid;
        float v = sm.t.zbuf[m];
        if (v > bv) { bv = v; bi = m; }
      }
      sm.t.rv[tid] = bv; sm.t.ri[tid] = bi; __syncthreads();
      for (int st = 128; st > 0; st >>= 1) {
        if (tid < st) {
          float v2 = sm.t.rv[tid + st]; int i2 = sm.t.ri[tid + st];
          if (v2 > sm.t.rv[tid] || (v2 == sm.t.rv[tid] && i2 < sm.t.ri[tid])) {
            sm.t.rv[tid] = v2; sm.t.ri[tid] = i2;
          }
        }
        __syncthreads();
      }
      if (tid == 0) { sm.t.chosen[t] = sm.t.ri[0]; sm.t.zbuf[sm.t.ri[0]] = -2.0f; }
      __syncthreads();
    }
    if (tid < 16) {
      int t = tid & 3, g2 = tid >> 2;
      int dh = g2 >> 1, dw = g2 & 1;
      int m = sm.t.chosen[t];
      int hi = (m >> 5) * 2 + dh, wi = (m & 31) * 2 + dw;
      sm.t.pos[g2 * 4 + t] = hi * 64 + wi;
    }
    __syncthreads();
    for (int i = tid; i < 16 * 256; i += 256) {
      int j = i >> 8, c = i & 255;
      sm.t.xg[j][c] = x[((size_t)b * 256 + c) * NSP + sm.t.pos[j]];
    }
    // gemv via LDS-staged W (four 64-c chunks)
    const int dd = tid & 63, jg = tid >> 6;
    const float bia = bkv[h * 64 + dd];
    float a4[4] = {bia, bia, bia, bia};
    for (int cc2 = 0; cc2 < 4; cc2++) {
      __syncthreads();
      for (int i = tid; i < 4096; i += 256) {
        int r = i >> 6, c = i & 63;
        sm.t.wl[r][c] = Wkv[(size_t)(h * 64 + r) * 256 + cc2 * 64 + c];
      }
      __syncthreads();
      #pragma unroll
      for (int jj = 0; jj < 4; jj++) {
        int j = jg * 4 + jj;
        float a = 0.f;
        #pragma unroll 8
        for (int c = 0; c < 64; c++) a += sm.t.xg[j][cc2 * 64 + c] * sm.t.wl[dd][c];
        a4[jj] += a;
      }
    }
    #pragma unroll
    for (int jj = 0; jj < 4; jj++) {
      int j = jg * 4 + jj;
      if (dd < 32) {
        g_tkKbf[((size_t)bh * 16 + j) * 32 + dd] = f2bf(a4[jj]);
      } else {
        int d = dd - 32;
        g_tkVT[((size_t)bh * 32 + d) * 32 + j] = f2bf(a4[jj]);
        g_tkVT[((size_t)bh * 32 + d) * 32 + 16 + j] = 0;
      }
    }
  } else {
    // ================= vpe =================
    const int idx = blockIdx.x - 16;
    const int c = idx & 255, b = idx >> 8;
    const int h = c >> 5, d = c & 31;
    const float* vrow = g_kv + ((size_t)b * 512 + h * 64 + 32 + d) * NUSP;
    for (int i = tid; i < 1024; i += 256) sm.v.src[i >> 5][i & 31] = vrow[i];
    if (tid < 49) sm.v.wk[tid] = Wpe[c * 49 + tid];
    __syncthreads();
    const float bia = bpe[c];
    for (int i = tid; i < 1024; i += 256) {
      int hu = i >> 5, wu = i & 31;
      float s = bia;
      #pragma unroll
      for (int kh = 0; kh < 7; kh++) {
        int ih = hu + kh - 3;
        if (ih < 0 || ih > 31) continue;
        #pragma unroll
        for (int kw = 0; kw < 7; kw++) {
          int iw = wu + kw - 3;
          if (iw < 0 || iw > 31) continue;
          s += sm.v.src[ih][iw] * sm.v.wk[kh * 7 + kw];
        }
      }
      sm.v.pl[hu][wu] = s;
    }
    __syncthreads();
    float* orow = g_vpe + ((size_t)b * 256 + c) * NSP;
    for (int i = tid; i < 4096; i += 256) {
      int hh = i >> 6, ww = i & 63;
      int ih = hh >> 1, iw = ww >> 1;
      int ih2 = (hh & 1) ? min(ih + 1, 31) : max(ih - 1, 0);
      int iw2 = (ww & 1) ? min(iw + 1, 31) : max(iw - 1, 0);
      float a  = 0.75f * sm.v.pl[ih][iw]  + 0.25f * sm.v.pl[ih][iw2];
      float bb = 0.75f * sm.v.pl[ih2][iw] + 0.25f * sm.v.pl[ih2][iw2];
      orow[i] = 0.75f * a + 0.25f * bb;
    }
  }
}

// ---------- MFMA flash v14: double-buffered K/V LDS (1 barrier/kt) ----------
// (kept from round-11; this round isolates it from the reverted W-prefetch)
__global__ __launch_bounds__(256) void k_flash(const float* __restrict__ bg) {
  const int bh = blockIdx.y;
  const int b = bh >> 3, h = bh & 7;
  const int tid = threadIdx.x;
  const int lane = tid & 63;
  const int w = tid >> 6;
  const int col = lane & 15;
  const int quad = lane >> 4;
  const int n0 = blockIdx.x * 64 + w * 16;

  __shared__ __align__(16) short Ps[4][16][88];
  __shared__ __align__(16) short Kb[2][64][40];   // [buf][m][d + pad8]
  __shared__ __align__(16) short Vb[2][32][72];   // [buf][d][m + pad8]
  short* PsA = &Ps[w][0][0];

  const short* kb = g_kbf + (size_t)bh * NUSP * 32;
  const short* vb = g_vbf + (size_t)bh * 32 * NUSP;

  // staging indices: K linear (kb[kt*2048 + tid*8]), V row-strided
  const int km = tid >> 2, kd = (tid & 3) * 8;   // Kb[.][m][kd..+7]
  const int vd = tid >> 3, vm = (tid & 7) * 8;   // Vb[.][d][vm..+7]

  short8 qfA = *(const short8*)&g_qbf[((size_t)bh * NSP + n0 + col) * 32 + quad * 8];

  f32x4 oA0 = {0,0,0,0}, oA1 = {0,0,0,0};
  float lA = 0.f;   // running exp-sum for q = n0 + col

  // prologue: tile 0 into buf0 (visible after iter-0's sync)
  {
    short8 ks = *(const short8*)&kb[tid * 8];
    short8 vs = *(const short8*)&vb[(size_t)vd * NUSP + vm];
    *(short8*)&Kb[0][km][kd] = ks;
    *(short8*)&Vb[0][vd][vm] = vs;
  }

  for (int kt = 0; kt < 16; kt++) {
    __syncthreads();   // buf[kt&1] ready; prior reads of buf[(kt+1)&1] done
    const int cur = kt & 1;
    short8 ks, vs;
    if (kt < 15) {     // issue next-tile loads; latency hides under compute
      ks = *(const short8*)&kb[(size_t)(kt + 1) * 2048 + tid * 8];
      vs = *(const short8*)&vb[(size_t)vd * NUSP + (kt + 1) * 64 + vm];
    }

    short8 kf[4];
    #pragma unroll
    for (int t = 0; t < 4; t++)
      kf[t] = *(const short8*)&Kb[cur][t * 16 + col][quad * 8];
    f32x4 sA[4];
    #pragma unroll
    for (int t = 0; t < 4; t++) {
      f32x4 z = {0,0,0,0};
      // swapped operands: D row = k-local (quad*4+r), D col = q (col)
      sA[t] = __builtin_amdgcn_mfma_f32_16x16x32_bf16(kf[t], qfA, z, 0, 0, 0);
    }
    #pragma unroll
    for (int t = 0; t < 4; t++) {
      float a0 = fexp2(sA[t][0]), a1 = fexp2(sA[t][1]);
      float a2 = fexp2(sA[t][2]), a3 = fexp2(sA[t][3]);
      lA += (a0 + a1) + (a2 + a3);
      uint2 wa; wa.x = pk2bf(a0, a1); wa.y = pk2bf(a2, a3);
      *(uint2*)&PsA[col * 88 + t * 16 + quad * 4] = wa;   // P[q=col][k=t*16+quad*4..+3]
    }
    short8 vf0 = *(const short8*)&Vb[cur][col][quad * 8];
    short8 vf1 = *(const short8*)&Vb[cur][col + 16][quad * 8];
    short8 vf2 = *(const short8*)&Vb[cur][col][32 + quad * 8];
    short8 vf3 = *(const short8*)&Vb[cur][col + 16][32 + quad * 8];
    short8 pA0 = *(const short8*)&PsA[col * 88 + quad * 8];
    short8 pA1 = *(const short8*)&PsA[col * 88 + 32 + quad * 8];
    oA0 = __builtin_amdgcn_mfma_f32_16x16x32_bf16(pA0, vf0, oA0, 0, 0, 0);
    oA1 = __builtin_amdgcn_mfma_f32_16x16x32_bf16(pA0, vf1, oA1, 0, 0, 0);
    oA0 = __builtin_amdgcn_mfma_f32_16x16x32_bf16(pA1, vf2, oA0, 0, 0, 0);
    oA1 = __builtin_amdgcn_mfma_f32_16x16x32_bf16(pA1, vf3, oA1, 0, 0, 0);

    if (kt < 15) {     // write next tile into the other buffer
      *(short8*)&Kb[cur ^ 1][km][kd] = ks;
      *(short8*)&Vb[cur ^ 1][vd][vm] = vs;
    }
  }
  // l total: sum the 4 quad-partials (each lane keeps sum for its q=col)
  lA += __shfl_xor(lA, 16, 64); lA += __shfl_xor(lA, 32, 64);

  // ===== epilogue (single tile) =====
  const float bg0 = bg[col], bg1 = bg[col + 16];
  short8 kff = *(const short8*)&g_tkKbf[(size_t)bh * 512 + col * 32 + quad * 8];
  short8 vt0 = *(const short8*)&g_tkVT[(size_t)bh * 1024 + col * 32 + quad * 8];
  short8 vt1 = *(const short8*)&g_tkVT[(size_t)bh * 1024 + (col + 16) * 32 + quad * 8];
  short8 b1a = *(const short8*)&g_wgbf[col * 64 + quad * 8];
  short8 b1b = *(const short8*)&g_wgbf[col * 64 + 32 + quad * 8];
  short8 b2a = *(const short8*)&g_wgbf[(col + 16) * 64 + quad * 8];
  short8 b2b = *(const short8*)&g_wgbf[(col + 16) * 64 + 32 + quad * 8];

  {
    const int nt = n0;
    f32x4 zf = {0,0,0,0};
    f32x4 co0, co1;
    #pragma unroll
    for (int r = 0; r < 4; r++) {
      // PV output rows are q = quad*4+r; fetch that q's l from lane (quad*4+r)
      float inv = 1.0f / __shfl(lA, quad * 4 + r, 64);
      co0[r] = oA0[r] * inv;
      co1[r] = oA1[r] * inv;
    }
    // fine scores (swapped): D row = fine-k quad*4+r, col = q
    f32x4 sfT = __builtin_amdgcn_mfma_f32_16x16x32_bf16(kff, qfA, zf, 0, 0, 0);
    float p0 = fexp2(sfT[0]), p1 = fexp2(sfT[1]);
    float p2 = fexp2(sfT[2]), p3 = fexp2(sfT[3]);
    float fls = (p0 + p1) + (p2 + p3);
    uint2 wf; wf.x = pk2bf(p0, p1); wf.y = pk2bf(p2, p3);
    *(uint2*)&PsA[col * 88 + quad * 4] = wf;   // P[q=col][k=quad*4..+3]
    fls += __shfl_xor(fls, 16, 64);
    fls += __shfl_xor(fls, 32, 64);
    short8 pff = {0, 0, 0, 0, 0, 0, 0, 0};
    if (quad < 2) pff = *(const short8*)&PsA[col * 88 + quad * 8];
    f32x4 rf0 = __builtin_amdgcn_mfma_f32_16x16x32_bf16(pff, vt0, zf, 0, 0, 0);
    f32x4 rf1 = __builtin_amdgcn_mfma_f32_16x16x32_bf16(pff, vt1, zf, 0, 0, 0);
    #pragma unroll
    for (int r = 0; r < 4; r++) {
      float inv = 1.0f / __shfl(fls, quad * 4 + r, 64);
      rf0[r] *= inv; rf1[r] *= inv;
    }
    // fusion tile [q][64]
    #pragma unroll
    for (int r = 0; r < 4; r++) {
      int q = quad * 4 + r;
      PsA[q * 88 + col]      = f2bf(co0[r]);
      PsA[q * 88 + col + 16] = f2bf(co1[r]);
      PsA[q * 88 + col + 32] = f2bf(rf0[r]);
      PsA[q * 88 + col + 48] = f2bf(rf1[r]);
    }
    short8 a1 = *(const short8*)&PsA[col * 88 + quad * 8];
    short8 a2 = *(const short8*)&PsA[col * 88 + 32 + quad * 8];
    f32x4 G0 = __builtin_amdgcn_mfma_f32_16x16x32_bf16(a1, b1a, zf, 0, 0, 0);
    G0 = __builtin_amdgcn_mfma_f32_16x16x32_bf16(a2, b1b, G0, 0, 0, 0);
    f32x4 G1 = __builtin_amdgcn_mfma_f32_16x16x32_bf16(a1, b2a, zf, 0, 0, 0);
    G1 = __builtin_amdgcn_mfma_f32_16x16x32_bf16(a2, b2b, G1, 0, 0, 0);
    const float* vpe0 = g_vpe + ((size_t)(b * 256 + h * 32 + col)) * NSP + nt;
    const float* vpe1 = g_vpe + ((size_t)(b * 256 + h * 32 + col + 16)) * NSP + nt;
    short* dstb = g_sumT + ((size_t)b * NSP + nt) * 256 + h * 32;
    #pragma unroll
    for (int r = 0; r < 4; r++) {
      int q = quad * 4 + r;
      float g0 = 1.0f / (1.0f + __expf(-(G0[r] + bg0)));
      float g1 = 1.0f / (1.0f + __expf(-(G1[r] + bg1)));
      float out0 = g0 * rf0[r] + (1.0f - g0) * co0[r] + vpe0[q];
      float out1 = g1 * rf1[r] + (1.0f - g1) * co1[r] + vpe1[q];
      dstb[(size_t)q * 256 + col]      = f2bf(out0);
      dstb[(size_t)q * 256 + col + 16] = f2bf(out1);
    }
  }
}

// ---------- k_gemm_proj: final projection, f32 out (B-tile LDS-staged) ----------
__global__ __launch_bounds__(256) void k_gemm_proj(const float* __restrict__ bias,
                                                   float* __restrict__ out) {
  __shared__ __align__(16) short Xs[64][264];
  const int b = blockIdx.z;
  const int o0 = blockIdx.y * 64;
  const int n0 = blockIdx.x * 64;
  const int tid = threadIdx.x;
  const int lane = tid & 63, w = tid >> 6, col = lane & 15, quad = lane >> 4;
  f32x4 acc[4] = {{0,0,0,0},{0,0,0,0},{0,0,0,0},{0,0,0,0}};
  stage_xt(Xs, g_sumT, b, n0, NSP, tid);
  gemm_mfma_lds(g_wbf + 196608, Xs, o0, w, col, quad, acc);
  #pragma unroll
  for (int r = 0; r < 4; r++) {
    int o = o0 + w * 16 + quad * 4 + r;
    float bv = bias[o];
    float* orow = out + ((size_t)b * 256 + o) * NSP + n0;
    #pragma unroll
    for (int t = 0; t < 4; t++)
      orow[t * 16 + col] = acc[t][r] + bv;
  }
}

extern "C" void kernel_launch(void* const* d_in, const int* in_sizes, int n_in,
                              void* d_out, int out_size, void* d_ws, size_t ws_size,
                              hipStream_t stream) {
  const float* x     = (const float*)d_in[0];
  const float* upper = (const float*)d_in[1];
  const float* Wq    = (const float*)d_in[2];
  const float* bq    = (const float*)d_in[3];
  const float* Wkv   = (const float*)d_in[4];
  const float* bkv   = (const float*)d_in[5];
  const float* Wproj = (const float*)d_in[6];
  const float* bproj = (const float*)d_in[7];
  const float* Wpe   = (const float*)d_in[8];
  const float* bpe   = (const float*)d_in[9];
  const float* Wg    = (const float*)d_in[10];
  const float* bg    = (const float*)d_in[11];
  float* out = (float*)d_out;
  (void)d_ws; (void)ws_size; (void)in_sizes; (void)n_in; (void)out_size;

  k_pack_in<<<dim3(1312), dim3(256), 0, stream>>>(x, upper, Wq, Wkv, Wproj, Wg);
  k_gemms<<<dim3(768), dim3(256), 0, stream>>>(bq, bkv);
  k_mid<<<dim3(528), dim3(256), 0, stream>>>(x, Wkv, bkv, Wpe, bpe);
  k_flash<<<dim3(64, 16), dim3(256), 0, stream>>>(bg);
  k_gemm_proj<<<dim3(64, 4, 2), dim3(256), 0, stream>>>(bproj, out);
}

// Round 13
// 169.804 us; speedup vs baseline: 1.0223x; 1.0223x over previous
//
#include <hip/hip_runtime.h>
#include <hip/hip_bf16.h>
#include <math.h>
#include <stdint.h>

// Problem constants
#define NB   2
#define NC   256
#define NSP  4096      // H*W
#define NUSP 1024      // Hu*Wu
#define NHEADS 8
#define HDIM 32
constexpr float SCL  = 0.17677669529663687f;   // 32^-0.5
constexpr float QSCL = 0.17677669529663687f * 1.4426950408889634f;  // SCL*log2(e)

typedef short short8 __attribute__((ext_vector_type(8)));
typedef float f32x4  __attribute__((ext_vector_type(4)));

__device__ __forceinline__ float fexp2(float x) {
#if __has_builtin(__builtin_amdgcn_exp2f)
  return __builtin_amdgcn_exp2f(x);
#else
  return exp2f(x);
#endif
}

// ---------- scratch (device globals referenced ONLY from device code) ----------
__device__ __align__(16) float g_kv    [NB * 512 * NUSP];  // conv-kv f32 [b][o=512][m]
__device__ __align__(16) float g_qm    [NB * NHEADS * HDIM];
__device__ __align__(16) float g_vpe   [NB * NC * NSP];    // [b][c][n]
// bf16 MFMA layouts
__device__ __align__(16) short g_qbf   [NB * NHEADS * NSP * HDIM];  // [bh][n][d] (pre-scaled SCL*log2e)
__device__ __align__(16) short g_kbf   [NB * NHEADS * NUSP * HDIM]; // [bh][m][d]
__device__ __align__(16) short g_vbf   [NB * NHEADS * HDIM * NUSP]; // [bh][d][m]
__device__ __align__(16) short g_tkKbf [NB * NHEADS * 16 * 32];     // [bh][key][d]
__device__ __align__(16) short g_tkVT  [NB * NHEADS * 32 * 32];     // [bh][d][keypad32]
__device__ __align__(16) short g_xT    [NB * NSP * 256];   // x^T   [b][n][c]
__device__ __align__(16) short g_uT    [NB * NUSP * 256];  // upper^T [b][m][c]
__device__ __align__(16) short g_sumT  [NB * NSP * 256];   // (attn+vpe)^T [b][n][c]
__device__ __align__(16) short g_wbf   [262144];           // Wq | Wkv | Wproj
__device__ __align__(16) short g_wgbf  [2048];             // Wg [32][64]

// f32 -> bf16 round-half-up
__device__ __forceinline__ short f2bf(float f) {
  return (short)((__float_as_uint(f) + 0x8000u) >> 16);
}

// pack two f32 -> two bf16 in a u32 (same round-half-up as f2bf)
__device__ __forceinline__ uint32_t pk2bf(float a, float b) {
  uint32_t lo = (__float_as_uint(a) + 0x8000u) >> 16;
  uint32_t hi = (__float_as_uint(b) + 0x8000u) & 0xffff0000u;
  return lo | hi;
}

// ---------- threefry2x32, key = (0, 42) ----------
__device__ __forceinline__ void threefry2x32_042(uint32_t x0, uint32_t x1,
                                                 uint32_t& r0, uint32_t& r1) {
  const uint32_t ks0 = 0u, ks1 = 42u, ks2 = 0u ^ 42u ^ 0x1BD11BDAu;
  x0 += ks0; x1 += ks1;
#define TFR(R) { x0 += x1; x1 = (x1 << (R)) | (x1 >> (32 - (R))); x1 ^= x0; }
  TFR(13) TFR(15) TFR(26) TFR(6)  x0 += ks1; x1 += ks2 + 1u;
  TFR(17) TFR(29) TFR(16) TFR(24) x0 += ks2; x1 += ks0 + 2u;
  TFR(13) TFR(15) TFR(26) TFR(6)  x0 += ks0; x1 += ks1 + 3u;
  TFR(17) TFR(29) TFR(16) TFR(24) x0 += ks1; x1 += ks2 + 4u;
  TFR(13) TFR(15) TFR(26) TFR(6)  x0 += ks2; x1 += ks0 + 5u;
#undef TFR
  r0 = x0; r1 = x1;
}

// gumbel, jax_threefry_partitionable path (verified round 5)
__device__ __forceinline__ float gumbel_at(uint32_t i) {
  uint32_t y0, y1;
  threefry2x32_042(0u, i, y0, y1);
  uint32_t bits = y0 ^ y1;
  uint32_t fb = (bits >> 9) | 0x3f800000u;
  float u = __uint_as_float(fb) - 1.0f;
  u = fmaxf(u, 1.17549435e-38f);
  return -logf(-logf(u));
}

// ---------- k_pack_in v2: fine grid (round-10, confirmed) ----------
__global__ __launch_bounds__(256) void k_pack_in(const float* __restrict__ x,
                                                 const float* __restrict__ upper,
                                                 const float* __restrict__ Wq,
                                                 const float* __restrict__ Wkv,
                                                 const float* __restrict__ Wproj,
                                                 const float* __restrict__ Wg) {
  const int blk = blockIdx.x;
  const int tid = threadIdx.x;
  if (blk < 1280) {
    __shared__ float Ls[32][65];
    const float* src;
    short* dst;
    int b, n0, Nsp, cc;
    if (blk < 1024) { int sec = blk >> 3; cc = blk & 7;
                      b = sec >> 6; n0 = (sec & 63) * 64; Nsp = NSP;
                      src = x + (size_t)b * 256 * NSP;  dst = g_xT + (size_t)b * NSP * 256; }
    else            { int s2 = (blk - 1024) >> 3; cc = (blk - 1024) & 7;
                      b = s2 >> 4; n0 = (s2 & 15) * 64; Nsp = NUSP;
                      src = upper + (size_t)b * 256 * NUSP; dst = g_uT + (size_t)b * NUSP * 256; }
    for (int i = tid; i < 2048; i += 256) {
      int d = i >> 6, nl = i & 63;
      Ls[d][nl] = src[(size_t)(cc * 32 + d) * Nsp + n0 + nl];
    }
    __syncthreads();
    int nl = tid >> 2, dseg = (tid & 3) * 8;
    short8 v;
    #pragma unroll
    for (int j = 0; j < 8; j++) v[j] = f2bf(Ls[dseg + j][nl]);
    *(short8*)&dst[(size_t)(n0 + nl) * 256 + cc * 32 + dseg] = v;
  } else {
    const int sec = blk - 1280;   // 0..31
    if (sec == 0) {
      for (int i = tid; i < 512; i += 256) g_qm[i] = 0.f;
      #pragma unroll
      for (int j = 0; j < 8; j++) g_wgbf[tid * 8 + j] = f2bf(Wg[tid * 8 + j]);
    }
    int base = sec * 8192 + tid * 32;
    const float* s;
    if (base < 65536)       s = Wq + base;
    else if (base < 196608) s = Wkv + (base - 65536);
    else                    s = Wproj + (base - 196608);
    short* d = g_wbf + base;
    #pragma unroll
    for (int j = 0; j < 8; j++) {
      float4 f = *(const float4*)&s[j * 4];
      d[j*4+0] = f2bf(f.x); d[j*4+1] = f2bf(f.y);
      d[j*4+2] = f2bf(f.z); d[j*4+3] = f2bf(f.w);
    }
  }
}

// ---------- B-operand LDS staging (round-9, confirmed -17us) ----------
__device__ __forceinline__ void stage_xt(short Xs[64][264],
                                         const short* __restrict__ ST,
                                         int b, int n0, int Nsp, int tid) {
  const short* src = ST + ((size_t)b * Nsp + n0) * 256;
  #pragma unroll
  for (int i = 0; i < 8; i++) {
    int idx = tid + i * 256;             // 0..2047 = 64 rows x 32 segs
    int row = idx >> 5, seg = (idx & 31) * 8;
    *(short8*)&Xs[row][seg] = *(const short8*)&src[(size_t)row * 256 + seg];
  }
  __syncthreads();
}

__device__ __forceinline__ void gemm_mfma_lds(const short* __restrict__ Wbf,
                                              const short Xs[64][264],
                                              int o0, int w, int col, int quad,
                                              f32x4 acc[4]) {
  const short* wrow = Wbf + (size_t)(o0 + w * 16 + col) * 256 + quad * 8;
  #pragma unroll
  for (int kc = 0; kc < 8; kc++) {
    short8 af = *(const short8*)&wrow[kc * 32];
    #pragma unroll
    for (int t = 0; t < 4; t++) {
      short8 bf = *(const short8*)&Xs[t * 16 + col][kc * 32 + quad * 8];
      acc[t] = __builtin_amdgcn_mfma_f32_16x16x32_bf16(af, bf, acc[t], 0, 0, 0);
    }
  }
}

// ---------- k_gemms: q conv (blocks 0..511) + kv conv (512..767), merged ----------
__global__ __launch_bounds__(256) void k_gemms(const float* __restrict__ bq,
                                               const float* __restrict__ bkv) {
  __shared__ float Ls[64][65];
  __shared__ __align__(16) short Xs[64][264];
  const int bx = blockIdx.x;
  const int tid = threadIdx.x;
  const int lane = tid & 63, w = tid >> 6, col = lane & 15, quad = lane >> 4;
  f32x4 acc[4] = {{0,0,0,0},{0,0,0,0},{0,0,0,0},{0,0,0,0}};

  if (bx < 512) {
    const int b = bx >> 8, o0 = ((bx >> 6) & 3) * 64, n0 = (bx & 63) * 64;
    stage_xt(Xs, g_xT, b, n0, NSP, tid);
    gemm_mfma_lds(g_wbf, Xs, o0, w, col, quad, acc);
    float sums[4];
    #pragma unroll
    for (int r = 0; r < 4; r++) {
      int ol = w * 16 + quad * 4 + r;
      float bv = bq[o0 + ol];
      float s = 0.f;
      #pragma unroll
      for (int t = 0; t < 4; t++) {
        float val = acc[t][r] + bv;
        Ls[ol][t * 16 + col] = val;
        s += val;
      }
      sums[r] = s;
    }
    #pragma unroll
    for (int st = 1; st < 16; st <<= 1)
      #pragma unroll
      for (int r = 0; r < 4; r++) sums[r] += __shfl_xor(sums[r], st, 64);
    if (col == 0) {
      #pragma unroll
      for (int r = 0; r < 4; r++)
        atomicAdd(&g_qm[b * 256 + o0 + w * 16 + quad * 4 + r], sums[r] * (1.0f / 4096.0f));
    }
    __syncthreads();
    int nl = tid >> 2, dseg = (tid & 3) * 8;
    #pragma unroll
    for (int hh = 0; hh < 2; hh++) {
      short8 v;
      #pragma unroll
      for (int j = 0; j < 8; j++) v[j] = f2bf(Ls[hh * 32 + dseg + j][nl] * QSCL);
      int bh = b * 8 + ((o0 + hh * 32) >> 5);
      *(short8*)&g_qbf[((size_t)bh * NSP + n0 + nl) * 32 + dseg] = v;
    }
  } else {
    const int idx = bx - 512;
    const int b = idx >> 7, o0 = ((idx >> 4) & 7) * 64, n0 = (idx & 15) * 64;
    stage_xt(Xs, g_uT, b, n0, NUSP, tid);
    gemm_mfma_lds(g_wbf + 65536, Xs, o0, w, col, quad, acc);
    #pragma unroll
    for (int r = 0; r < 4; r++) {
      int ol = w * 16 + quad * 4 + r;
      float bv = bkv[o0 + ol];
      float* orow = g_kv + ((size_t)b * 512 + o0 + ol) * NUSP + n0;
      #pragma unroll
      for (int t = 0; t < 4; t++) {
        float val = acc[t][r] + bv;
        orow[t * 16 + col] = val;
        Ls[ol][t * 16 + col] = val;
      }
    }
    __syncthreads();
    const int bh = b * 8 + (o0 >> 6);
    {  // k rows [0,32) -> kbf transpose
      int m = tid >> 2, dseg = (tid & 3) * 8;
      short8 v;
      #pragma unroll
      for (int j = 0; j < 8; j++) v[j] = f2bf(Ls[dseg + j][m]);
      *(short8*)&g_kbf[((size_t)bh * NUSP + n0 + m) * 32 + dseg] = v;
    }
    {  // v rows [32,64) -> vbf straight
      int d = tid >> 3, m8 = (tid & 7) * 8;
      short8 v;
      #pragma unroll
      for (int j = 0; j < 8; j++) v[j] = f2bf(Ls[32 + d][m8 + j]);
      *(short8*)&g_vbf[((size_t)bh * 32 + d) * NUSP + n0 + m8] = v;
    }
  }
}

// ---------- k_mid: topk (blocks 0..15) + vpe (16..527), merged ----------
union MidSmem {
  struct {
    float zbuf[1024]; float qml[32]; float rv[256]; int ri[256];
    int chosen[4]; int pos[16]; float xg[16][256]; float wl[64][65];
  } t;
  struct {
    float src[32][33]; float pl[32][33]; float wk[49];
  } v;
};

__global__ __launch_bounds__(256) void k_mid(const float* __restrict__ x,
                                             const float* __restrict__ Wkv,
                                             const float* __restrict__ bkv,
                                             const float* __restrict__ Wpe,
                                             const float* __restrict__ bpe) {
  __shared__ MidSmem sm;
  const int tid = threadIdx.x;
  if (blockIdx.x < 16) {
    // ================= topk =================
    const int bh = blockIdx.x;
    const int b = bh >> 3, h = bh & 7;
    if (tid < 32) sm.t.qml[tid] = g_qm[bh * 32 + tid];
    __syncthreads();
    const float* kbase = g_kv + ((size_t)b * 512 + h * 64) * NUSP;
    float zv[4];
    #pragma unroll
    for (int r = 0; r < 4; r++) {
      int m = r * 256 + tid;
      float dot = 0.f;
      #pragma unroll 8
      for (int d = 0; d < 32; d++) dot += sm.t.qml[d] * kbase[(size_t)d * NUSP + m];
      float z = dot * SCL + gumbel_at((uint32_t)(bh * 1024 + m));
      zv[r] = z; sm.t.zbuf[m] = z;
    }
    __syncthreads();
    float mx = fmaxf(fmaxf(zv[0], zv[1]), fmaxf(zv[2], zv[3]));
    sm.t.rv[tid] = mx; __syncthreads();
    for (int st = 128; st > 0; st >>= 1) {
      if (tid < st) sm.t.rv[tid] = fmaxf(sm.t.rv[tid], sm.t.rv[tid + st]);
      __syncthreads();
    }
    float zmax = sm.t.rv[0]; __syncthreads();
    float sp = 0.f; float ev[4];
    #pragma unroll
    for (int r = 0; r < 4; r++) { ev[r] = __expf(zv[r] - zmax); sp += ev[r]; }
    sm.t.rv[tid] = sp; __syncthreads();
    for (int st = 128; st > 0; st >>= 1) {
      if (tid < st) sm.t.rv[tid] += sm.t.rv[tid + st];
      __syncthreads();
    }
    float ssum = sm.t.rv[0]; __syncthreads();
    #pragma unroll
    for (int r = 0; r < 4; r++) sm.t.zbuf[r * 256 + tid] = ev[r] / ssum;
    __syncthreads();
    for (int t = 0; t < 4; t++) {
      float bv = -2.0f; int bi = 0;
      #pragma unroll
      for (int r = 0; r < 4; r++) {
        int m = r * 256 + tid;
        float v = sm.t.zbuf[m];
        if (v > bv) { bv = v; bi = m; }
      }
      sm.t.rv[tid] = bv; sm.t.ri[tid] = bi; __syncthreads();
      for (int st = 128; st > 0; st >>= 1) {
        if (tid < st) {
          float v2 = sm.t.rv[tid + st]; int i2 = sm.t.ri[tid + st];
          if (v2 > sm.t.rv[tid] || (v2 == sm.t.rv[tid] && i2 < sm.t.ri[tid])) {
            sm.t.rv[tid] = v2; sm.t.ri[tid] = i2;
          }
        }
        __syncthreads();
      }
      if (tid == 0) { sm.t.chosen[t] = sm.t.ri[0]; sm.t.zbuf[sm.t.ri[0]] = -2.0f; }
      __syncthreads();
    }
    if (tid < 16) {
      int t = tid & 3, g2 = tid >> 2;
      int dh = g2 >> 1, dw = g2 & 1;
      int m = sm.t.chosen[t];
      int hi = (m >> 5) * 2 + dh, wi = (m & 31) * 2 + dw;
      sm.t.pos[g2 * 4 + t] = hi * 64 + wi;
    }
    __syncthreads();
    for (int i = tid; i < 16 * 256; i += 256) {
      int j = i >> 8, c = i & 255;
      sm.t.xg[j][c] = x[((size_t)b * 256 + c) * NSP + sm.t.pos[j]];
    }
    // gemv via LDS-staged W (four 64-c chunks)
    const int dd = tid & 63, jg = tid >> 6;
    const float bia = bkv[h * 64 + dd];
    float a4[4] = {bia, bia, bia, bia};
    for (int cc2 = 0; cc2 < 4; cc2++) {
      __syncthreads();
      for (int i = tid; i < 4096; i += 256) {
        int r = i >> 6, c = i & 63;
        sm.t.wl[r][c] = Wkv[(size_t)(h * 64 + r) * 256 + cc2 * 64 + c];
      }
      __syncthreads();
      #pragma unroll
      for (int jj = 0; jj < 4; jj++) {
        int j = jg * 4 + jj;
        float a = 0.f;
        #pragma unroll 8
        for (int c = 0; c < 64; c++) a += sm.t.xg[j][cc2 * 64 + c] * sm.t.wl[dd][c];
        a4[jj] += a;
      }
    }
    #pragma unroll
    for (int jj = 0; jj < 4; jj++) {
      int j = jg * 4 + jj;
      if (dd < 32) {
        g_tkKbf[((size_t)bh * 16 + j) * 32 + dd] = f2bf(a4[jj]);
      } else {
        int d = dd - 32;
        g_tkVT[((size_t)bh * 32 + d) * 32 + j] = f2bf(a4[jj]);
        g_tkVT[((size_t)bh * 32 + d) * 32 + 16 + j] = 0;
      }
    }
  } else {
    // ================= vpe =================
    const int idx = blockIdx.x - 16;
    const int c = idx & 255, b = idx >> 8;
    const int h = c >> 5, d = c & 31;
    const float* vrow = g_kv + ((size_t)b * 512 + h * 64 + 32 + d) * NUSP;
    for (int i = tid; i < 1024; i += 256) sm.v.src[i >> 5][i & 31] = vrow[i];
    if (tid < 49) sm.v.wk[tid] = Wpe[c * 49 + tid];
    __syncthreads();
    const float bia = bpe[c];
    for (int i = tid; i < 1024; i += 256) {
      int hu = i >> 5, wu = i & 31;
      float s = bia;
      #pragma unroll
      for (int kh = 0; kh < 7; kh++) {
        int ih = hu + kh - 3;
        if (ih < 0 || ih > 31) continue;
        #pragma unroll
        for (int kw = 0; kw < 7; kw++) {
          int iw = wu + kw - 3;
          if (iw < 0 || iw > 31) continue;
          s += sm.v.src[ih][iw] * sm.v.wk[kh * 7 + kw];
        }
      }
      sm.v.pl[hu][wu] = s;
    }
    __syncthreads();
    float* orow = g_vpe + ((size_t)b * 256 + c) * NSP;
    for (int i = tid; i < 4096; i += 256) {
      int hh = i >> 6, ww = i & 63;
      int ih = hh >> 1, iw = ww >> 1;
      int ih2 = (hh & 1) ? min(ih + 1, 31) : max(ih - 1, 0);
      int iw2 = (ww & 1) ? min(iw + 1, 31) : max(iw - 1, 0);
      float a  = 0.75f * sm.v.pl[ih][iw]  + 0.25f * sm.v.pl[ih][iw2];
      float bb = 0.75f * sm.v.pl[ih2][iw] + 0.25f * sm.v.pl[ih2][iw2];
      orow[i] = 0.75f * a + 0.25f * bb;
    }
  }
}

// ---------- MFMA flash v13: 1 q-tile/wave + LDS K/V staging + pipelined loads ----------
// (round-10 exact; round-11/12 dbuf variant measured +2.7us -> reverted)
__global__ __launch_bounds__(256) void k_flash(const float* __restrict__ bg) {
  const int bh = blockIdx.y;
  const int b = bh >> 3, h = bh & 7;
  const int tid = threadIdx.x;
  const int lane = tid & 63;
  const int w = tid >> 6;
  const int col = lane & 15;
  const int quad = lane >> 4;
  const int n0 = blockIdx.x * 64 + w * 16;

  __shared__ __align__(16) short Ps[4][16][88];
  __shared__ __align__(16) short Kb[64][40];   // [m][d + pad8]
  __shared__ __align__(16) short Vb[32][72];   // [d][m + pad8]
  short* PsA = &Ps[w][0][0];

  const short* kb = g_kbf + (size_t)bh * NUSP * 32;
  const short* vb = g_vbf + (size_t)bh * 32 * NUSP;

  // staging indices: K linear (kb[kt*2048 + tid*8]), V row-strided
  const int km = tid >> 2, kd = (tid & 3) * 8;   // Kb[m][kd..+7]
  const int vd = tid >> 3, vm = (tid & 7) * 8;   // Vb[d][vm..+7]

  short8 qfA = *(const short8*)&g_qbf[((size_t)bh * NSP + n0 + col) * 32 + quad * 8];

  f32x4 oA0 = {0,0,0,0}, oA1 = {0,0,0,0};
  float lA = 0.f;   // running exp-sum for q = n0 + col

  // prologue: tile 0 into registers
  short8 ks = *(const short8*)&kb[tid * 8];
  short8 vs = *(const short8*)&vb[(size_t)vd * NUSP + vm];

  for (int kt = 0; kt < 16; kt++) {
    __syncthreads();   // all waves done reading previous K/V tile
    *(short8*)&Kb[km][kd] = ks;
    *(short8*)&Vb[vd][vm] = vs;
    __syncthreads();   // tile ready
    if (kt < 15) {     // issue next-tile loads; latency hides under compute below
      ks = *(const short8*)&kb[(size_t)(kt + 1) * 2048 + tid * 8];
      vs = *(const short8*)&vb[(size_t)vd * NUSP + (kt + 1) * 64 + vm];
    }

    short8 kf[4];
    #pragma unroll
    for (int t = 0; t < 4; t++)
      kf[t] = *(const short8*)&Kb[t * 16 + col][quad * 8];
    f32x4 sA[4];
    #pragma unroll
    for (int t = 0; t < 4; t++) {
      f32x4 z = {0,0,0,0};
      // swapped operands: D row = k-local (quad*4+r), D col = q (col)
      sA[t] = __builtin_amdgcn_mfma_f32_16x16x32_bf16(kf[t], qfA, z, 0, 0, 0);
    }
    #pragma unroll
    for (int t = 0; t < 4; t++) {
      float a0 = fexp2(sA[t][0]), a1 = fexp2(sA[t][1]);
      float a2 = fexp2(sA[t][2]), a3 = fexp2(sA[t][3]);
      lA += (a0 + a1) + (a2 + a3);
      uint2 wa; wa.x = pk2bf(a0, a1); wa.y = pk2bf(a2, a3);
      *(uint2*)&PsA[col * 88 + t * 16 + quad * 4] = wa;   // P[q=col][k=t*16+quad*4..+3]
    }
    short8 vf0 = *(const short8*)&Vb[col][quad * 8];
    short8 vf1 = *(const short8*)&Vb[col + 16][quad * 8];
    short8 vf2 = *(const short8*)&Vb[col][32 + quad * 8];
    short8 vf3 = *(const short8*)&Vb[col + 16][32 + quad * 8];
    short8 pA0 = *(const short8*)&PsA[col * 88 + quad * 8];
    short8 pA1 = *(const short8*)&PsA[col * 88 + 32 + quad * 8];
    oA0 = __builtin_amdgcn_mfma_f32_16x16x32_bf16(pA0, vf0, oA0, 0, 0, 0);
    oA1 = __builtin_amdgcn_mfma_f32_16x16x32_bf16(pA0, vf1, oA1, 0, 0, 0);
    oA0 = __builtin_amdgcn_mfma_f32_16x16x32_bf16(pA1, vf2, oA0, 0, 0, 0);
    oA1 = __builtin_amdgcn_mfma_f32_16x16x32_bf16(pA1, vf3, oA1, 0, 0, 0);
  }
  // l total: sum the 4 quad-partials (each lane keeps sum for its q=col)
  lA += __shfl_xor(lA, 16, 64); lA += __shfl_xor(lA, 32, 64);

  // ===== epilogue (single tile) =====
  const float bg0 = bg[col], bg1 = bg[col + 16];
  short8 kff = *(const short8*)&g_tkKbf[(size_t)bh * 512 + col * 32 + quad * 8];
  short8 vt0 = *(const short8*)&g_tkVT[(size_t)bh * 1024 + col * 32 + quad * 8];
  short8 vt1 = *(const short8*)&g_tkVT[(size_t)bh * 1024 + (col + 16) * 32 + quad * 8];
  short8 b1a = *(const short8*)&g_wgbf[col * 64 + quad * 8];
  short8 b1b = *(const short8*)&g_wgbf[col * 64 + 32 + quad * 8];
  short8 b2a = *(const short8*)&g_wgbf[(col + 16) * 64 + quad * 8];
  short8 b2b = *(const short8*)&g_wgbf[(col + 16) * 64 + 32 + quad * 8];

  {
    const int nt = n0;
    f32x4 zf = {0,0,0,0};
    f32x4 co0, co1;
    #pragma unroll
    for (int r = 0; r < 4; r++) {
      // PV output rows are q = quad*4+r; fetch that q's l from lane (quad*4+r)
      float inv = 1.0f / __shfl(lA, quad * 4 + r, 64);
      co0[r] = oA0[r] * inv;
      co1[r] = oA1[r] * inv;
    }
    // fine scores (swapped): D row = fine-k quad*4+r, col = q
    f32x4 sfT = __builtin_amdgcn_mfma_f32_16x16x32_bf16(kff, qfA, zf, 0, 0, 0);
    float p0 = fexp2(sfT[0]), p1 = fexp2(sfT[1]);
    float p2 = fexp2(sfT[2]), p3 = fexp2(sfT[3]);
    float fls = (p0 + p1) + (p2 + p3);
    uint2 wf; wf.x = pk2bf(p0, p1); wf.y = pk2bf(p2, p3);
    *(uint2*)&PsA[col * 88 + quad * 4] = wf;   // P[q=col][k=quad*4..+3]
    fls += __shfl_xor(fls, 16, 64);
    fls += __shfl_xor(fls, 32, 64);
    short8 pff = {0, 0, 0, 0, 0, 0, 0, 0};
    if (quad < 2) pff = *(const short8*)&PsA[col * 88 + quad * 8];
    f32x4 rf0 = __builtin_amdgcn_mfma_f32_16x16x32_bf16(pff, vt0, zf, 0, 0, 0);
    f32x4 rf1 = __builtin_amdgcn_mfma_f32_16x16x32_bf16(pff, vt1, zf, 0, 0, 0);
    #pragma unroll
    for (int r = 0; r < 4; r++) {
      float inv = 1.0f / __shfl(fls, quad * 4 + r, 64);
      rf0[r] *= inv; rf1[r] *= inv;
    }
    // fusion tile [q][64]
    #pragma unroll
    for (int r = 0; r < 4; r++) {
      int q = quad * 4 + r;
      PsA[q * 88 + col]      = f2bf(co0[r]);
      PsA[q * 88 + col + 16] = f2bf(co1[r]);
      PsA[q * 88 + col + 32] = f2bf(rf0[r]);
      PsA[q * 88 + col + 48] = f2bf(rf1[r]);
    }
    short8 a1 = *(const short8*)&PsA[col * 88 + quad * 8];
    short8 a2 = *(const short8*)&PsA[col * 88 + 32 + quad * 8];
    f32x4 G0 = __builtin_amdgcn_mfma_f32_16x16x32_bf16(a1, b1a, zf, 0, 0, 0);
    G0 = __builtin_amdgcn_mfma_f32_16x16x32_bf16(a2, b1b, G0, 0, 0, 0);
    f32x4 G1 = __builtin_amdgcn_mfma_f32_16x16x32_bf16(a1, b2a, zf, 0, 0, 0);
    G1 = __builtin_amdgcn_mfma_f32_16x16x32_bf16(a2, b2b, G1, 0, 0, 0);
    const float* vpe0 = g_vpe + ((size_t)(b * 256 + h * 32 + col)) * NSP + nt;
    const float* vpe1 = g_vpe + ((size_t)(b * 256 + h * 32 + col + 16)) * NSP + nt;
    short* dstb = g_sumT + ((size_t)b * NSP + nt) * 256 + h * 32;
    #pragma unroll
    for (int r = 0; r < 4; r++) {
      int q = quad * 4 + r;
      float g0 = 1.0f / (1.0f + __expf(-(G0[r] + bg0)));
      float g1 = 1.0f / (1.0f + __expf(-(G1[r] + bg1)));
      float out0 = g0 * rf0[r] + (1.0f - g0) * co0[r] + vpe0[q];
      float out1 = g1 * rf1[r] + (1.0f - g1) * co1[r] + vpe1[q];
      dstb[(size_t)q * 256 + col]      = f2bf(out0);
      dstb[(size_t)q * 256 + col + 16] = f2bf(out1);
    }
  }
}

// ---------- k_gemm_proj: final projection, f32 out (B-tile LDS-staged) ----------
__global__ __launch_bounds__(256) void k_gemm_proj(const float* __restrict__ bias,
                                                   float* __restrict__ out) {
  __shared__ __align__(16) short Xs[64][264];
  const int b = blockIdx.z;
  const int o0 = blockIdx.y * 64;
  const int n0 = blockIdx.x * 64;
  const int tid = threadIdx.x;
  const int lane = tid & 63, w = tid >> 6, col = lane & 15, quad = lane >> 4;
  f32x4 acc[4] = {{0,0,0,0},{0,0,0,0},{0,0,0,0},{0,0,0,0}};
  stage_xt(Xs, g_sumT, b, n0, NSP, tid);
  gemm_mfma_lds(g_wbf + 196608, Xs, o0, w, col, quad, acc);
  #pragma unroll
  for (int r = 0; r < 4; r++) {
    int o = o0 + w * 16 + quad * 4 + r;
    float bv = bias[o];
    float* orow = out + ((size_t)b * 256 + o) * NSP + n0;
    #pragma unroll
    for (int t = 0; t < 4; t++)
      orow[t * 16 + col] = acc[t][r] + bv;
  }
}

extern "C" void kernel_launch(void* const* d_in, const int* in_sizes, int n_in,
                              void* d_out, int out_size, void* d_ws, size_t ws_size,
                              hipStream_t stream) {
  const float* x     = (const float*)d_in[0];
  const float* upper = (const float*)d_in[1];
  const float* Wq    = (const float*)d_in[2];
  const float* bq    = (const float*)d_in[3];
  const float* Wkv   = (const float*)d_in[4];
  const float* bkv   = (const float*)d_in[5];
  const float* Wproj = (const float*)d_in[6];
  const float* bproj = (const float*)d_in[7];
  const float* Wpe   = (const float*)d_in[8];
  const float* bpe   = (const float*)d_in[9];
  const float* Wg    = (const float*)d_in[10];
  const float* bg    = (const float*)d_in[11];
  float* out = (float*)d_out;
  (void)d_ws; (void)ws_size; (void)in_sizes; (void)n_in; (void)out_size;

  k_pack_in<<<dim3(1312), dim3(256), 0, stream>>>(x, upper, Wq, Wkv, Wproj, Wg);
  k_gemms<<<dim3(768), dim3(256), 0, stream>>>(bq, bkv);
  k_mid<<<dim3(528), dim3(256), 0, stream>>>(x, Wkv, bkv, Wpe, bpe);
  k_flash<<<dim3(64, 16), dim3(256), 0, stream>>>(bg);
  k_gemm_proj<<<dim3(64, 4, 2), dim3(256), 0, stream>>>(bproj, out);
}